// Round 3
// baseline (766.927 us; speedup 1.0000x reference)
//
#include <hip/hip_runtime.h>
#include <hip/hip_bf16.h>
#include <cstdint>
#include <cstddef>

// Problem constants (AttentionLayerEnhance: B=4, L=S=2048, D=512, H=8, window=32)
// I/O dtypes: ALL inputs float32, BOTH outputs float32 (reference contract).
// Internal compute: bf16 MFMA with f32 accumulation (tolerance is bf16-scale).
#define D_MODEL 512
#define N_HEADS 8
#define HDIM 64
#define SEQ 2048
#define B_SZ 4
#define M_TOT (B_SZ * SEQ)                 // 8192 rows for all projections
#define ATTN_ROWS (B_SZ * N_HEADS * SEQ)   // 65536 rows of the attn matrix
#define PROJ_ELEMS ((size_t)M_TOT * D_MODEL)   // 4,194,304

typedef __bf16 bf16x8 __attribute__((ext_vector_type(8)));
typedef float  f32x4  __attribute__((ext_vector_type(4)));

__device__ __forceinline__ unsigned short f2bf(float x) {
    __bf16 b = (__bf16)x;
    return __builtin_bit_cast(unsigned short, b);
}
__device__ __forceinline__ float bf2f(unsigned short u) {
    __bf16 b = __builtin_bit_cast(__bf16, u);
    return (float)b;
}

// ---------------------------------------------------------------------------
// Zero-fill (dense f32 attn output region, 537 MB) — 16B stores, grid-stride.
// ---------------------------------------------------------------------------
__global__ __launch_bounds__(256) void fill_zero(float4* __restrict__ p, size_t n4) {
    size_t i = (size_t)blockIdx.x * blockDim.x + threadIdx.x;
    size_t stride = (size_t)gridDim.x * blockDim.x;
    float4 z; z.x = 0.f; z.y = 0.f; z.z = 0.f; z.w = 0.f;
    for (; i < n4; i += stride) p[i] = z;
}

// ---------------------------------------------------------------------------
// f32 -> bf16 conversion for Q/K/V inputs. 8 elems/thread.
// ---------------------------------------------------------------------------
struct CvtArgs {
    const float* src[3];
    unsigned short* dst[3];
};

__global__ __launch_bounds__(256) void cvt_k(CvtArgs ca) {
    const int z = blockIdx.z;
    const size_t i = ((size_t)blockIdx.x * 256 + threadIdx.x) * 8;
    const float* src = ca.src[z];
    float4 a = *(const float4*)&src[i];
    float4 b = *(const float4*)&src[i + 4];
    unsigned short outv[8];
    outv[0] = f2bf(a.x); outv[1] = f2bf(a.y); outv[2] = f2bf(a.z); outv[3] = f2bf(a.w);
    outv[4] = f2bf(b.x); outv[5] = f2bf(b.y); outv[6] = f2bf(b.z); outv[7] = f2bf(b.w);
    *(uint4*)&ca.dst[z][i] = *(const uint4*)outv;
}

// ---------------------------------------------------------------------------
// 512x512 transpose (f32 W[k][n] -> bf16 Wt[n][k]). z selects weight.
// ---------------------------------------------------------------------------
struct TransArgs {
    const float* W[4];
    unsigned short* Wt[4];
};

__global__ void transpose_k(TransArgs ta) {
    __shared__ float tile[32][33];
    const int z = blockIdx.z;
    const float* W = ta.W[z];
    unsigned short* Wt = ta.Wt[z];
    int x = blockIdx.x * 32 + threadIdx.x;
    int y0 = blockIdx.y * 32;
    for (int j = threadIdx.y; j < 32; j += 8)
        tile[j][threadIdx.x] = W[(size_t)(y0 + j) * D_MODEL + x];
    __syncthreads();
    int xo = blockIdx.y * 32 + threadIdx.x;
    int yo0 = blockIdx.x * 32;
    for (int j = threadIdx.y; j < 32; j += 8)
        Wt[(size_t)(yo0 + j) * D_MODEL + xo] = f2bf(tile[threadIdx.x][j]);
}

// ---------------------------------------------------------------------------
// bf16 GEMM: C[M,512] = A[M,512] * W + bias, W given transposed (Wt[N,K]).
// 128x128 tile, BK=64, 4 waves (2x2 of 64x64), mfma_f32_16x16x32_bf16,
// 4x4 accumulators/wave. LDS rows padded to 72 elems (16B-aligned, 2-way
// bank alias = free). F32OUT: final projection writes f32 to d_out.
// ---------------------------------------------------------------------------
struct GemmArgs {
    const unsigned short* A[3];
    const unsigned short* Wt[3];
    const float* bias[3];
    void* C[3];
};

#define LDSTRIDE 72

template <int F32OUT>
__global__ __launch_bounds__(256, 2) void gemm_bt(GemmArgs ga) {
    __shared__ __align__(16) unsigned short lsA[128 * LDSTRIDE];
    __shared__ __align__(16) unsigned short lsB[128 * LDSTRIDE];

    const int z = blockIdx.z;
    const unsigned short* __restrict__ A  = ga.A[z];
    const unsigned short* __restrict__ Wt = ga.Wt[z];
    const float* __restrict__ bias        = ga.bias[z];

    const int m0 = blockIdx.x * 128;
    const int n0 = blockIdx.y * 128;
    const int tid = threadIdx.x;
    const int lane = tid & 63;
    const int wid = tid >> 6;
    const int wm = (wid >> 1) * 64;
    const int wn = (wid & 1) * 64;
    const int lrow = lane & 15;
    const int quad = lane >> 4;

    f32x4 acc[4][4];
#pragma unroll
    for (int i = 0; i < 4; ++i)
#pragma unroll
        for (int j = 0; j < 4; ++j)
            acc[i][j] = (f32x4){0.f, 0.f, 0.f, 0.f};

    for (int kt = 0; kt < D_MODEL; kt += 64) {
        __syncthreads();
#pragma unroll
        for (int p = 0; p < 4; ++p) {
            int c = p * 256 + tid;
            int r = c >> 3;
            int col = (c & 7) << 3;
            *(uint4*)&lsA[r * LDSTRIDE + col] =
                *(const uint4*)&A[(size_t)(m0 + r) * D_MODEL + kt + col];
        }
#pragma unroll
        for (int p = 0; p < 4; ++p) {
            int c = p * 256 + tid;
            int r = c >> 3;
            int col = (c & 7) << 3;
            *(uint4*)&lsB[r * LDSTRIDE + col] =
                *(const uint4*)&Wt[(size_t)(n0 + r) * D_MODEL + kt + col];
        }
        __syncthreads();
#pragma unroll
        for (int ks = 0; ks < 2; ++ks) {
            const int ko = ks * 32 + quad * 8;
            bf16x8 af[4], bfr[4];
#pragma unroll
            for (int mt = 0; mt < 4; ++mt)
                af[mt] = *(const bf16x8*)&lsA[(wm + mt * 16 + lrow) * LDSTRIDE + ko];
#pragma unroll
            for (int nt = 0; nt < 4; ++nt)
                bfr[nt] = *(const bf16x8*)&lsB[(wn + nt * 16 + lrow) * LDSTRIDE + ko];
#pragma unroll
            for (int mt = 0; mt < 4; ++mt)
#pragma unroll
                for (int nt = 0; nt < 4; ++nt)
                    acc[mt][nt] = __builtin_amdgcn_mfma_f32_16x16x32_bf16(
                        af[mt], bfr[nt], acc[mt][nt], 0, 0, 0);
        }
    }

    // Epilogue: C/D layout col=lane&15, row=quad*4+reg (m89-verified).
#pragma unroll
    for (int nt = 0; nt < 4; ++nt) {
        const int gcol = n0 + wn + nt * 16 + lrow;
        const float bv = bias[gcol];
#pragma unroll
        for (int mt = 0; mt < 4; ++mt) {
            const int grow = m0 + wm + mt * 16 + quad * 4;
#pragma unroll
            for (int r = 0; r < 4; ++r) {
                const float v = acc[mt][nt][r] + bv;
                if (F32OUT)
                    ((float*)ga.C[z])[(size_t)(grow + r) * D_MODEL + gcol] = v;
                else
                    ((unsigned short*)ga.C[z])[(size_t)(grow + r) * D_MODEL + gcol] = f2bf(v);
            }
        }
    }
}

// ---------------------------------------------------------------------------
// Band attention: one wave per (b,h,t). Valid keys: s in [max(0,t-16), t],
// cnt <= 17. lane = d (dk=64). Decay multiplies the logit (per reference).
// attn values written f32 to the pre-zeroed dense matrix; ctx bf16 to ws.
// ---------------------------------------------------------------------------
__global__ __launch_bounds__(256, 4) void attn_k(
    const unsigned short* __restrict__ Q,
    const unsigned short* __restrict__ K,
    const unsigned short* __restrict__ V,
    const float* __restrict__ gamma_p,
    float* __restrict__ attn_out,
    unsigned short* __restrict__ ctx) {
    const int wid = threadIdx.x >> 6;
    const int lane = threadIdx.x & 63;
    const int idx = blockIdx.x * 4 + wid;     // ((b*H + h)*SEQ + t)
    const int t = idx & (SEQ - 1);
    const int bh = idx >> 11;
    const int h = bh & (N_HEADS - 1);
    const int b = bh >> 3;

    const float g = gamma_p[0];
    int s0 = t - 16;
    if (s0 < 0) s0 = 0;
    const int cnt = t - s0 + 1;

    const size_t qrow = (size_t)b * SEQ + t;
    const int qcol = h * HDIM + lane;
    const float q = bf2f(Q[qrow * D_MODEL + qcol]);
    const float rs = 0.044194173824159216f;   // 1/sqrt(512)
    const size_t krowbase = (size_t)b * SEQ;

    float myscore = -__builtin_inff();
    float m = -__builtin_inff();
    for (int j = 0; j < cnt; ++j) {
        const int s = s0 + j;
        const float kv = bf2f(K[(krowbase + s) * D_MODEL + qcol]);
        float part = q * kv;
#pragma unroll
        for (int off = 32; off > 0; off >>= 1)
            part += __shfl_xor(part, off, 64);
        const float score = part * rs * __expf(-g * (float)(t - s));
        if (lane == j) myscore = score;
        m = fmaxf(m, score);
    }

    const float p = (lane < cnt) ? __expf(myscore - m) : 0.f;
    float l = p;
#pragma unroll
    for (int off = 32; off > 0; off >>= 1)
        l += __shfl_xor(l, off, 64);
    const float inv = 1.f / l;

    if (lane < cnt)
        attn_out[(size_t)idx * SEQ + s0 + lane] = p * inv;

    float acc = 0.f;
    for (int j = 0; j < cnt; ++j) {
        const float pj = __shfl(p, j, 64) * inv;
        const float vv = bf2f(V[(krowbase + s0 + j) * D_MODEL + qcol]);
        acc = fmaf(pj, vv, acc);
    }
    ctx[qrow * D_MODEL + qcol] = f2bf(acc);
}

// ---------------------------------------------------------------------------
// ws layout (bf16 elements, 16B aligned):
//  [Qin|Kin|Vin: 3x8MB][WT: 4x512KB][Qp|Kp|Vp: 3x8MB][Ctx: 8MB]  ~= 58 MB
// ---------------------------------------------------------------------------
extern "C" void kernel_launch(void* const* d_in, const int* in_sizes, int n_in,
                              void* d_out, int out_size, void* d_ws, size_t ws_size,
                              hipStream_t stream) {
    const float* queries = (const float*)d_in[0];
    const float* keys    = (const float*)d_in[1];
    const float* values  = (const float*)d_in[2];
    // d_in[3] attn_mask: fixed causal triu — folded analytically.
    const float* Wq = (const float*)d_in[4];
    const float* bq = (const float*)d_in[5];
    const float* Wk = (const float*)d_in[6];
    const float* bk = (const float*)d_in[7];
    const float* Wv = (const float*)d_in[8];
    const float* bv = (const float*)d_in[9];
    const float* Wo = (const float*)d_in[10];
    const float* bo = (const float*)d_in[11];
    const float* gamma = (const float*)d_in[12];

    char* ws = (char*)d_ws;
    unsigned short* Qin = (unsigned short*)ws;
    unsigned short* Kin = Qin + PROJ_ELEMS;
    unsigned short* Vin = Kin + PROJ_ELEMS;
    unsigned short* WT  = Vin + PROJ_ELEMS;
    unsigned short* WqT = WT;
    unsigned short* WkT = WT + 262144;
    unsigned short* WvT = WT + 2 * 262144;
    unsigned short* WoT = WT + 3 * 262144;
    unsigned short* Qp  = WT + 4 * 262144;
    unsigned short* Kp  = Qp + PROJ_ELEMS;
    unsigned short* Vp  = Kp + PROJ_ELEMS;
    unsigned short* Ctx = Vp + PROJ_ELEMS;

    float* out_p  = (float*)d_out;            // [8192,512] f32
    float* attn_p = out_p + PROJ_ELEMS;       // [65536,2048] f32

    // 1) zero the dense attn output (537 MB f32)
    const size_t n4 = (size_t)ATTN_ROWS * SEQ / 4;    // float4 count
    fill_zero<<<8192, 256, 0, stream>>>((float4*)attn_p, n4);

    // 2) convert Q/K/V inputs f32 -> bf16
    CvtArgs ca;
    ca.src[0] = queries; ca.src[1] = keys; ca.src[2] = values;
    ca.dst[0] = Qin;     ca.dst[1] = Kin;  ca.dst[2] = Vin;
    cvt_k<<<dim3(PROJ_ELEMS / (256 * 8), 1, 3), 256, 0, stream>>>(ca);

    // 3) weight transposes (f32 in, bf16 out)
    TransArgs ta;
    ta.W[0] = Wq;  ta.W[1] = Wk;  ta.W[2] = Wv;  ta.W[3] = Wo;
    ta.Wt[0] = WqT; ta.Wt[1] = WkT; ta.Wt[2] = WvT; ta.Wt[3] = WoT;
    transpose_k<<<dim3(16, 16, 4), dim3(32, 8), 0, stream>>>(ta);

    // 4) fused QKV projections (bf16 out to ws)
    GemmArgs gq;
    gq.A[0] = Qin;   gq.A[1] = Kin;  gq.A[2] = Vin;
    gq.Wt[0] = WqT;  gq.Wt[1] = WkT; gq.Wt[2] = WvT;
    gq.bias[0] = bq; gq.bias[1] = bk; gq.bias[2] = bv;
    gq.C[0] = Qp;    gq.C[1] = Kp;   gq.C[2] = Vp;
    gemm_bt<0><<<dim3(M_TOT / 128, D_MODEL / 128, 3), 256, 0, stream>>>(gq);

    // 5) band attention (+ f32 attn band values + bf16 context)
    attn_k<<<ATTN_ROWS / 4, 256, 0, stream>>>(Qp, Kp, Vp, gamma, attn_p, Ctx);

    // 6) output projection -> f32 out region of d_out
    GemmArgs go;
    go.A[0] = Ctx;   go.Wt[0] = WoT; go.bias[0] = bo; go.C[0] = out_p;
    go.A[1] = Ctx;   go.Wt[1] = WoT; go.bias[1] = bo; go.C[1] = out_p;
    go.A[2] = Ctx;   go.Wt[2] = WoT; go.bias[2] = bo; go.C[2] = out_p;
    gemm_bt<1><<<dim3(M_TOT / 128, D_MODEL / 128, 1), 256, 0, stream>>>(go);
}

// Round 4
// 706.339 us; speedup vs baseline: 1.0858x; 1.0858x over previous
//
#include <hip/hip_runtime.h>
#include <hip/hip_bf16.h>
#include <cstdint>
#include <cstddef>

// Problem constants (AttentionLayerEnhance: B=4, L=S=2048, D=512, H=8, window=32)
// I/O dtypes: ALL inputs float32, BOTH outputs float32 (reference contract).
// Internal compute: bf16 MFMA / bf16-product f32-accum (tolerance is bf16-scale).
#define D_MODEL 512
#define N_HEADS 8
#define HDIM 64
#define SEQ 2048
#define B_SZ 4
#define M_TOT (B_SZ * SEQ)                 // 8192 rows for all projections
#define ATTN_ROWS (B_SZ * N_HEADS * SEQ)   // 65536 rows of the attn matrix
#define PROJ_ELEMS ((size_t)M_TOT * D_MODEL)   // 4,194,304

typedef __bf16 bf16x8 __attribute__((ext_vector_type(8)));
typedef float  f32x4  __attribute__((ext_vector_type(4)));

__device__ __forceinline__ unsigned short f2bf(float x) {
    __bf16 b = (__bf16)x;
    return __builtin_bit_cast(unsigned short, b);
}
__device__ __forceinline__ float bf2f(unsigned short u) {
    __bf16 b = __builtin_bit_cast(__bf16, u);
    return (float)b;
}

// ---------------------------------------------------------------------------
// Zero-fill (dense f32 attn output region, 537 MB) — 16B stores, grid-stride.
// ---------------------------------------------------------------------------
__global__ __launch_bounds__(256) void fill_zero(float4* __restrict__ p, size_t n4) {
    size_t i = (size_t)blockIdx.x * blockDim.x + threadIdx.x;
    size_t stride = (size_t)gridDim.x * blockDim.x;
    float4 z; z.x = 0.f; z.y = 0.f; z.z = 0.f; z.w = 0.f;
    for (; i < n4; i += stride) p[i] = z;
}

// ---------------------------------------------------------------------------
// f32 -> bf16 conversion for Q/K/V inputs. 8 elems/thread.
// ---------------------------------------------------------------------------
struct CvtArgs {
    const float* src[3];
    unsigned short* dst[3];
};

__global__ __launch_bounds__(256) void cvt_k(CvtArgs ca) {
    const int z = blockIdx.z;
    const size_t i = ((size_t)blockIdx.x * 256 + threadIdx.x) * 8;
    const float* src = ca.src[z];
    float4 a = *(const float4*)&src[i];
    float4 b = *(const float4*)&src[i + 4];
    unsigned short outv[8];
    outv[0] = f2bf(a.x); outv[1] = f2bf(a.y); outv[2] = f2bf(a.z); outv[3] = f2bf(a.w);
    outv[4] = f2bf(b.x); outv[5] = f2bf(b.y); outv[6] = f2bf(b.z); outv[7] = f2bf(b.w);
    *(uint4*)&ca.dst[z][i] = *(const uint4*)outv;
}

// ---------------------------------------------------------------------------
// 512x512 transpose (f32 W[k][n] -> bf16 Wt[n][k]). z selects weight.
// ---------------------------------------------------------------------------
struct TransArgs {
    const float* W[4];
    unsigned short* Wt[4];
};

__global__ void transpose_k(TransArgs ta) {
    __shared__ float tile[32][33];
    const int z = blockIdx.z;
    const float* W = ta.W[z];
    unsigned short* Wt = ta.Wt[z];
    int x = blockIdx.x * 32 + threadIdx.x;
    int y0 = blockIdx.y * 32;
    for (int j = threadIdx.y; j < 32; j += 8)
        tile[j][threadIdx.x] = W[(size_t)(y0 + j) * D_MODEL + x];
    __syncthreads();
    int xo = blockIdx.y * 32 + threadIdx.x;
    int yo0 = blockIdx.x * 32;
    for (int j = threadIdx.y; j < 32; j += 8)
        Wt[(size_t)(yo0 + j) * D_MODEL + xo] = f2bf(tile[threadIdx.x][j]);
}

// ---------------------------------------------------------------------------
// bf16 GEMM: C[M,512] = A[M,512] * W + bias, W given transposed (Wt[N,K]).
// 128x128 tile, BK=64, 4 waves (2x2 of 64x64), mfma_f32_16x16x32_bf16,
// 4x4 accumulators/wave. LDS rows padded to 72 elems. F32OUT: f32 C writes.
// ---------------------------------------------------------------------------
struct GemmArgs {
    const unsigned short* A[3];
    const unsigned short* Wt[3];
    const float* bias[3];
    void* C[3];
};

#define LDSTRIDE 72

template <int F32OUT>
__global__ __launch_bounds__(256, 2) void gemm_bt(GemmArgs ga) {
    __shared__ __align__(16) unsigned short lsA[128 * LDSTRIDE];
    __shared__ __align__(16) unsigned short lsB[128 * LDSTRIDE];

    const int z = blockIdx.z;
    const unsigned short* __restrict__ A  = ga.A[z];
    const unsigned short* __restrict__ Wt = ga.Wt[z];
    const float* __restrict__ bias        = ga.bias[z];

    const int m0 = blockIdx.x * 128;
    const int n0 = blockIdx.y * 128;
    const int tid = threadIdx.x;
    const int lane = tid & 63;
    const int wid = tid >> 6;
    const int wm = (wid >> 1) * 64;
    const int wn = (wid & 1) * 64;
    const int lrow = lane & 15;
    const int quad = lane >> 4;

    f32x4 acc[4][4];
#pragma unroll
    for (int i = 0; i < 4; ++i)
#pragma unroll
        for (int j = 0; j < 4; ++j)
            acc[i][j] = (f32x4){0.f, 0.f, 0.f, 0.f};

    for (int kt = 0; kt < D_MODEL; kt += 64) {
        __syncthreads();
#pragma unroll
        for (int p = 0; p < 4; ++p) {
            int c = p * 256 + tid;
            int r = c >> 3;
            int col = (c & 7) << 3;
            *(uint4*)&lsA[r * LDSTRIDE + col] =
                *(const uint4*)&A[(size_t)(m0 + r) * D_MODEL + kt + col];
        }
#pragma unroll
        for (int p = 0; p < 4; ++p) {
            int c = p * 256 + tid;
            int r = c >> 3;
            int col = (c & 7) << 3;
            *(uint4*)&lsB[r * LDSTRIDE + col] =
                *(const uint4*)&Wt[(size_t)(n0 + r) * D_MODEL + kt + col];
        }
        __syncthreads();
#pragma unroll
        for (int ks = 0; ks < 2; ++ks) {
            const int ko = ks * 32 + quad * 8;
            bf16x8 af[4], bfr[4];
#pragma unroll
            for (int mt = 0; mt < 4; ++mt)
                af[mt] = *(const bf16x8*)&lsA[(wm + mt * 16 + lrow) * LDSTRIDE + ko];
#pragma unroll
            for (int nt = 0; nt < 4; ++nt)
                bfr[nt] = *(const bf16x8*)&lsB[(wn + nt * 16 + lrow) * LDSTRIDE + ko];
#pragma unroll
            for (int mt = 0; mt < 4; ++mt)
#pragma unroll
                for (int nt = 0; nt < 4; ++nt)
                    acc[mt][nt] = __builtin_amdgcn_mfma_f32_16x16x32_bf16(
                        af[mt], bfr[nt], acc[mt][nt], 0, 0, 0);
        }
    }

    // Epilogue: C/D layout col=lane&15, row=quad*4+reg (m89-verified).
#pragma unroll
    for (int nt = 0; nt < 4; ++nt) {
        const int gcol = n0 + wn + nt * 16 + lrow;
        const float bv = bias[gcol];
#pragma unroll
        for (int mt = 0; mt < 4; ++mt) {
            const int grow = m0 + wm + mt * 16 + quad * 4;
#pragma unroll
            for (int r = 0; r < 4; ++r) {
                const float v = acc[mt][nt][r] + bv;
                if (F32OUT)
                    ((float*)ga.C[z])[(size_t)(grow + r) * D_MODEL + gcol] = v;
                else
                    ((unsigned short*)ga.C[z])[(size_t)(grow + r) * D_MODEL + gcol] = f2bf(v);
            }
        }
    }
}

// ---------------------------------------------------------------------------
// Tiled band attention. One block per (b, h, 64-row t-tile). K/V rows
// [t0-16, t0+63] staged in LDS (80 rows x 64, stride 72 => <=2-way bank
// alias). Lane = (r = row 0..15 within wave's 16 rows, c = d-quarter 0..3).
// Scores: 16 reg-FMAs per key + 2 quad shuffles. Softmax fully per-lane
// (decay depends only on j: t-s = 16-j). PV in registers.
// ---------------------------------------------------------------------------
#define KV_ROWS 80
#define LROW 72

__device__ __forceinline__ void load16f(const unsigned short* p, float* out) {
    bf16x8 a = *(const bf16x8*)p;
    bf16x8 b = *(const bf16x8*)(p + 8);
#pragma unroll
    for (int i = 0; i < 8; ++i) { out[i] = (float)a[i]; out[8 + i] = (float)b[i]; }
}

__global__ __launch_bounds__(256, 4) void attn2_k(
    const unsigned short* __restrict__ Q,
    const unsigned short* __restrict__ K,
    const unsigned short* __restrict__ V,
    const float* __restrict__ gamma_p,
    float* __restrict__ attn_out,
    unsigned short* __restrict__ ctx) {
    __shared__ __align__(16) unsigned short lk[KV_ROWS * LROW];
    __shared__ __align__(16) unsigned short lv[KV_ROWS * LROW];

    const int bh = blockIdx.y;                 // b*8 + h
    const int t0 = blockIdx.x * 64;
    const int b = bh >> 3;
    const int h = bh & 7;
    const int tid = threadIdx.x;
    const int w = tid >> 6;
    const int lane = tid & 63;
    const int r = lane >> 2;
    const int c = lane & 3;

    const float g = gamma_p[0];
    const float rs = 0.044194173824159216f;    // 1/sqrt(512)

    // Stage K/V rows [t0-16, t0+63] (zeros for negative rows).
    const size_t srcbase = (size_t)b * SEQ * D_MODEL + (size_t)h * HDIM;
    for (int idx = tid; idx < KV_ROWS * 8; idx += 256) {
        const int row = idx >> 3;
        const int ch = (idx & 7) * 8;
        const int grow = t0 - 16 + row;
        uint4 kv4 = {0, 0, 0, 0};
        uint4 vv4 = {0, 0, 0, 0};
        if (grow >= 0) {
            const size_t off = srcbase + (size_t)grow * D_MODEL + ch;
            kv4 = *(const uint4*)&K[off];
            vv4 = *(const uint4*)&V[off];
        }
        *(uint4*)&lk[row * LROW + ch] = kv4;
        *(uint4*)&lv[row * LROW + ch] = vv4;
    }
    __syncthreads();

    // Per-lane Q segment: row gr, d-cols c*16..c*16+15 (within this head).
    const int gr = t0 + w * 16 + r;            // global t
    const size_t qoff = srcbase + (size_t)gr * D_MODEL + c * 16;
    float qv[16];
    load16f(&Q[qoff], qv);

    // Scores over the 17-key band (j: s = gr-16+j).
    const int lr0 = w * 16 + r;                // LDS row for j=0
    float scr[17];
#pragma unroll
    for (int j = 0; j < 17; ++j) {
        float kvv[16];
        load16f(&lk[(lr0 + j) * LROW + c * 16], kvv);
        float part = 0.f;
#pragma unroll
        for (int i = 0; i < 16; ++i) part = fmaf(qv[i], kvv[i], part);
        part += __shfl_xor(part, 1, 64);
        part += __shfl_xor(part, 2, 64);
        const float dec = __expf(-g * (float)(16 - j));
        scr[j] = part * rs * dec;
        if (gr - 16 + j < 0) scr[j] = -__builtin_inff();
    }

    // Per-lane softmax (j=16 always valid => m finite).
    float m = scr[0];
#pragma unroll
    for (int j = 1; j < 17; ++j) m = fmaxf(m, scr[j]);
    float l = 0.f;
#pragma unroll
    for (int j = 0; j < 17; ++j) { scr[j] = __expf(scr[j] - m); l += scr[j]; }
    const float inv = 1.f / l;

    // PV: out[gr][c*16+i] = sum_j p[j] * V[s][c*16+i].
    float acc[16];
#pragma unroll
    for (int i = 0; i < 16; ++i) acc[i] = 0.f;
#pragma unroll
    for (int j = 0; j < 17; ++j) {
        float vv[16];
        load16f(&lv[(lr0 + j) * LROW + c * 16], vv);
#pragma unroll
        for (int i = 0; i < 16; ++i) acc[i] = fmaf(scr[j], vv[i], acc[i]);
    }

    // ctx store (bf16, 32 B/lane contiguous per quad-row).
    unsigned short outv[16];
#pragma unroll
    for (int i = 0; i < 16; ++i) outv[i] = f2bf(acc[i] * inv);
    *(uint4*)&ctx[qoff]     = *(const uint4*)&outv[0];
    *(uint4*)&ctx[qoff + 8] = *(const uint4*)&outv[8];

    // Band attn writes (f32, pre-zeroed matrix). Quad lanes split the 17 js.
    const size_t arow = ((size_t)bh * SEQ + gr) * SEQ;
    for (int j = c; j < 17; j += 4) {
        const int s = gr - 16 + j;
        if (s >= 0) attn_out[arow + s] = scr[j] * inv;
    }
}

// ---------------------------------------------------------------------------
// ws layout (bf16 elements, 16B aligned):
//  [Qin|Kin|Vin: 3x8MB][WT: 4x512KB][Qp|Kp|Vp: 3x8MB][Ctx: 8MB]  ~= 58 MB
// ---------------------------------------------------------------------------
extern "C" void kernel_launch(void* const* d_in, const int* in_sizes, int n_in,
                              void* d_out, int out_size, void* d_ws, size_t ws_size,
                              hipStream_t stream) {
    const float* queries = (const float*)d_in[0];
    const float* keys    = (const float*)d_in[1];
    const float* values  = (const float*)d_in[2];
    // d_in[3] attn_mask: fixed causal triu — folded analytically.
    const float* Wq = (const float*)d_in[4];
    const float* bq = (const float*)d_in[5];
    const float* Wk = (const float*)d_in[6];
    const float* bk = (const float*)d_in[7];
    const float* Wv = (const float*)d_in[8];
    const float* bv = (const float*)d_in[9];
    const float* Wo = (const float*)d_in[10];
    const float* bo = (const float*)d_in[11];
    const float* gamma = (const float*)d_in[12];

    char* ws = (char*)d_ws;
    unsigned short* Qin = (unsigned short*)ws;
    unsigned short* Kin = Qin + PROJ_ELEMS;
    unsigned short* Vin = Kin + PROJ_ELEMS;
    unsigned short* WT  = Vin + PROJ_ELEMS;
    unsigned short* WqT = WT;
    unsigned short* WkT = WT + 262144;
    unsigned short* WvT = WT + 2 * 262144;
    unsigned short* WoT = WT + 3 * 262144;
    unsigned short* Qp  = WT + 4 * 262144;
    unsigned short* Kp  = Qp + PROJ_ELEMS;
    unsigned short* Vp  = Kp + PROJ_ELEMS;
    unsigned short* Ctx = Vp + PROJ_ELEMS;

    float* out_p  = (float*)d_out;            // [8192,512] f32
    float* attn_p = out_p + PROJ_ELEMS;       // [65536,2048] f32

    // 1) zero the dense attn output (537 MB f32)
    const size_t n4 = (size_t)ATTN_ROWS * SEQ / 4;    // float4 count
    fill_zero<<<8192, 256, 0, stream>>>((float4*)attn_p, n4);

    // 2) convert Q/K/V inputs f32 -> bf16
    CvtArgs ca;
    ca.src[0] = queries; ca.src[1] = keys; ca.src[2] = values;
    ca.dst[0] = Qin;     ca.dst[1] = Kin;  ca.dst[2] = Vin;
    cvt_k<<<dim3(PROJ_ELEMS / (256 * 8), 1, 3), 256, 0, stream>>>(ca);

    // 3) weight transposes (f32 in, bf16 out)
    TransArgs ta;
    ta.W[0] = Wq;  ta.W[1] = Wk;  ta.W[2] = Wv;  ta.W[3] = Wo;
    ta.Wt[0] = WqT; ta.Wt[1] = WkT; ta.Wt[2] = WvT; ta.Wt[3] = WoT;
    transpose_k<<<dim3(16, 16, 4), dim3(32, 8), 0, stream>>>(ta);

    // 4) fused QKV projections (bf16 out to ws)
    GemmArgs gq;
    gq.A[0] = Qin;   gq.A[1] = Kin;  gq.A[2] = Vin;
    gq.Wt[0] = WqT;  gq.Wt[1] = WkT; gq.Wt[2] = WvT;
    gq.bias[0] = bq; gq.bias[1] = bk; gq.bias[2] = bv;
    gq.C[0] = Qp;    gq.C[1] = Kp;   gq.C[2] = Vp;
    gemm_bt<0><<<dim3(M_TOT / 128, D_MODEL / 128, 3), 256, 0, stream>>>(gq);

    // 5) tiled band attention (+ f32 attn band values + bf16 context)
    attn2_k<<<dim3(SEQ / 64, B_SZ * N_HEADS), 256, 0, stream>>>(
        Qp, Kp, Vp, gamma, attn_p, Ctx);

    // 6) output projection -> f32 out region of d_out
    GemmArgs go;
    go.A[0] = Ctx;   go.Wt[0] = WoT; go.bias[0] = bo; go.C[0] = out_p;
    go.A[1] = Ctx;   go.Wt[1] = WoT; go.bias[1] = bo; go.C[1] = out_p;
    go.A[2] = Ctx;   go.Wt[2] = WoT; go.bias[2] = bo; go.C[2] = out_p;
    gemm_bt<1><<<dim3(M_TOT / 128, D_MODEL / 128, 1), 256, 0, stream>>>(go);
}

// Round 5
// 654.079 us; speedup vs baseline: 1.1725x; 1.0799x over previous
//
#include <hip/hip_runtime.h>
#include <hip/hip_bf16.h>
#include <cstdint>
#include <cstddef>

// Problem constants (AttentionLayerEnhance: B=4, L=S=2048, D=512, H=8, window=32)
// I/O: all inputs f32, both outputs f32. Internal: bf16 MFMA, f32 accum.
#define D_MODEL 512
#define N_HEADS 8
#define HDIM 64
#define SEQ 2048
#define B_SZ 4
#define M_TOT (B_SZ * SEQ)                 // 8192 rows for all projections
#define ATTN_ROWS (B_SZ * N_HEADS * SEQ)   // 65536 rows of the attn matrix
#define PROJ_ELEMS ((size_t)M_TOT * D_MODEL)   // 4,194,304

typedef __bf16 bf16x8 __attribute__((ext_vector_type(8)));
typedef float  f32x4  __attribute__((ext_vector_type(4)));

__device__ __forceinline__ unsigned short f2bf(float x) {
    __bf16 b = (__bf16)x;
    return __builtin_bit_cast(unsigned short, b);
}
__device__ __forceinline__ float bf2f(unsigned short u) {
    __bf16 b = __builtin_bit_cast(__bf16, u);
    return (float)b;
}

// ---------------------------------------------------------------------------
// 512x512 transpose (f32 W[k][n] -> bf16 Wt[n][k]). z selects weight.
// ---------------------------------------------------------------------------
struct TransArgs {
    const float* W[4];
    unsigned short* Wt[4];
};

__global__ void transpose_k(TransArgs ta) {
    __shared__ float tile[32][33];
    const int z = blockIdx.z;
    const float* W = ta.W[z];
    unsigned short* Wt = ta.Wt[z];
    int x = blockIdx.x * 32 + threadIdx.x;
    int y0 = blockIdx.y * 32;
    for (int j = threadIdx.y; j < 32; j += 8)
        tile[j][threadIdx.x] = W[(size_t)(y0 + j) * D_MODEL + x];
    __syncthreads();
    int xo = blockIdx.y * 32 + threadIdx.x;
    int yo0 = blockIdx.x * 32;
    for (int j = threadIdx.y; j < 32; j += 8)
        Wt[(size_t)(yo0 + j) * D_MODEL + xo] = f2bf(tile[threadIdx.x][j]);
}

// ---------------------------------------------------------------------------
// bf16 GEMM: C[M,512] = A[M,512] * W + bias. A source is F32 (converted to
// bf16 in-register during LDS staging). W given transposed (Wt[N,K] bf16).
// 128x128 tile, BK=64, 4 waves (2x2 of 64x64), mfma_f32_16x16x32_bf16,
// 4x4 accumulators/wave. LDS rows padded to 72 elems (2-way alias = free).
// F32OUT=1: f32 C writes (d_out); else bf16 (ws).
// ---------------------------------------------------------------------------
struct GemmArgs {
    const float* A[3];
    const unsigned short* Wt[3];
    const float* bias[3];
    void* C[3];
};

#define LDSTRIDE 72

template <int F32OUT>
__global__ __launch_bounds__(256, 2) void gemm_bt(GemmArgs ga) {
    __shared__ __align__(16) unsigned short lsA[128 * LDSTRIDE];
    __shared__ __align__(16) unsigned short lsB[128 * LDSTRIDE];

    const int z = blockIdx.z;
    const float* __restrict__ A           = ga.A[z];
    const unsigned short* __restrict__ Wt = ga.Wt[z];
    const float* __restrict__ bias        = ga.bias[z];

    const int m0 = blockIdx.x * 128;
    const int n0 = blockIdx.y * 128;
    const int tid = threadIdx.x;
    const int lane = tid & 63;
    const int wid = tid >> 6;
    const int wm = (wid >> 1) * 64;
    const int wn = (wid & 1) * 64;
    const int lrow = lane & 15;
    const int quad = lane >> 4;

    f32x4 acc[4][4];
#pragma unroll
    for (int i = 0; i < 4; ++i)
#pragma unroll
        for (int j = 0; j < 4; ++j)
            acc[i][j] = (f32x4){0.f, 0.f, 0.f, 0.f};

    for (int kt = 0; kt < D_MODEL; kt += 64) {
        __syncthreads();
#pragma unroll
        for (int p = 0; p < 4; ++p) {
            int c = p * 256 + tid;
            int r = c >> 3;
            int col = (c & 7) << 3;
            const float* src = &A[(size_t)(m0 + r) * D_MODEL + kt + col];
            float4 a0 = *(const float4*)src;
            float4 a1 = *(const float4*)(src + 4);
            unsigned short t8[8];
            t8[0] = f2bf(a0.x); t8[1] = f2bf(a0.y); t8[2] = f2bf(a0.z); t8[3] = f2bf(a0.w);
            t8[4] = f2bf(a1.x); t8[5] = f2bf(a1.y); t8[6] = f2bf(a1.z); t8[7] = f2bf(a1.w);
            *(uint4*)&lsA[r * LDSTRIDE + col] = *(const uint4*)t8;
        }
#pragma unroll
        for (int p = 0; p < 4; ++p) {
            int c = p * 256 + tid;
            int r = c >> 3;
            int col = (c & 7) << 3;
            *(uint4*)&lsB[r * LDSTRIDE + col] =
                *(const uint4*)&Wt[(size_t)(n0 + r) * D_MODEL + kt + col];
        }
        __syncthreads();
#pragma unroll
        for (int ks = 0; ks < 2; ++ks) {
            const int ko = ks * 32 + quad * 8;
            bf16x8 af[4], bfr[4];
#pragma unroll
            for (int mt = 0; mt < 4; ++mt)
                af[mt] = *(const bf16x8*)&lsA[(wm + mt * 16 + lrow) * LDSTRIDE + ko];
#pragma unroll
            for (int nt = 0; nt < 4; ++nt)
                bfr[nt] = *(const bf16x8*)&lsB[(wn + nt * 16 + lrow) * LDSTRIDE + ko];
#pragma unroll
            for (int mt = 0; mt < 4; ++mt)
#pragma unroll
                for (int nt = 0; nt < 4; ++nt)
                    acc[mt][nt] = __builtin_amdgcn_mfma_f32_16x16x32_bf16(
                        af[mt], bfr[nt], acc[mt][nt], 0, 0, 0);
        }
    }

    // Epilogue: C/D layout col=lane&15, row=quad*4+reg (m89-verified).
#pragma unroll
    for (int nt = 0; nt < 4; ++nt) {
        const int gcol = n0 + wn + nt * 16 + lrow;
        const float bv = bias[gcol];
#pragma unroll
        for (int mt = 0; mt < 4; ++mt) {
            const int grow = m0 + wm + mt * 16 + quad * 4;
#pragma unroll
            for (int r = 0; r < 4; ++r) {
                const float v = acc[mt][nt][r] + bv;
                if (F32OUT)
                    ((float*)ga.C[z])[(size_t)(grow + r) * D_MODEL + gcol] = v;
                else
                    ((unsigned short*)ga.C[z])[(size_t)(grow + r) * D_MODEL + gcol] = f2bf(v);
            }
        }
    }
}

// ---------------------------------------------------------------------------
// Tiled band attention + full attn-row writer. One block per (b, h, 64-row
// t-tile). K/V rows [t0-16, t0+63] staged in LDS. Lane = (r = row 0..15,
// c = d-quarter 0..3). Scores: 16 reg-FMAs per key + 2 quad shuffles.
// Softmax per-lane. Probabilities go to LDS pband; then the whole block
// streams the 64 full rows (2048 f32: zeros + band) with float4 stores —
// this replaces the separate 537 MB zero-fill pass entirely.
// ---------------------------------------------------------------------------
#define KV_ROWS 80
#define LROW 72

__device__ __forceinline__ void load16f(const unsigned short* p, float* out) {
    bf16x8 a = *(const bf16x8*)p;
    bf16x8 b = *(const bf16x8*)(p + 8);
#pragma unroll
    for (int i = 0; i < 8; ++i) { out[i] = (float)a[i]; out[8 + i] = (float)b[i]; }
}

__global__ __launch_bounds__(256, 4) void attn2_k(
    const unsigned short* __restrict__ Q,
    const unsigned short* __restrict__ K,
    const unsigned short* __restrict__ V,
    const float* __restrict__ gamma_p,
    float* __restrict__ attn_out,
    float* __restrict__ ctx) {
    __shared__ __align__(16) unsigned short lk[KV_ROWS * LROW];
    __shared__ __align__(16) unsigned short lv[KV_ROWS * LROW];
    __shared__ float pband[64][20];            // [row-in-tile][j], padded

    const int bh = blockIdx.y;                 // b*8 + h
    const int t0 = blockIdx.x * 64;
    const int b = bh >> 3;
    const int h = bh & 7;
    const int tid = threadIdx.x;
    const int w = tid >> 6;
    const int lane = tid & 63;
    const int r = lane >> 2;
    const int c = lane & 3;

    const float g = gamma_p[0];
    const float rs = 0.044194173824159216f;    // 1/sqrt(512)

    // Stage K/V rows [t0-16, t0+63] (zeros for negative rows).
    const size_t srcbase = (size_t)b * SEQ * D_MODEL + (size_t)h * HDIM;
    for (int idx = tid; idx < KV_ROWS * 8; idx += 256) {
        const int row = idx >> 3;
        const int ch = (idx & 7) * 8;
        const int grow = t0 - 16 + row;
        uint4 kv4 = {0, 0, 0, 0};
        uint4 vv4 = {0, 0, 0, 0};
        if (grow >= 0) {
            const size_t off = srcbase + (size_t)grow * D_MODEL + ch;
            kv4 = *(const uint4*)&K[off];
            vv4 = *(const uint4*)&V[off];
        }
        *(uint4*)&lk[row * LROW + ch] = kv4;
        *(uint4*)&lv[row * LROW + ch] = vv4;
    }
    __syncthreads();

    // Per-lane Q segment: row gr, d-cols c*16..c*16+15 (within this head).
    const int gr = t0 + w * 16 + r;            // global t
    const size_t qoff = srcbase + (size_t)gr * D_MODEL + c * 16;
    float qv[16];
    load16f(&Q[qoff], qv);

    // Scores over the 17-key band (j: s = gr-16+j).
    const int lr0 = w * 16 + r;                // LDS row for j=0
    float scr[17];
#pragma unroll
    for (int j = 0; j < 17; ++j) {
        float kvv[16];
        load16f(&lk[(lr0 + j) * LROW + c * 16], kvv);
        float part = 0.f;
#pragma unroll
        for (int i = 0; i < 16; ++i) part = fmaf(qv[i], kvv[i], part);
        part += __shfl_xor(part, 1, 64);
        part += __shfl_xor(part, 2, 64);       // all 4 quad lanes now have full dot
        const float dec = __expf(-g * (float)(16 - j));
        scr[j] = part * rs * dec;
        if (gr - 16 + j < 0) scr[j] = -__builtin_inff();
    }

    // Per-lane softmax (j=16 always valid => m finite).
    float m = scr[0];
#pragma unroll
    for (int j = 1; j < 17; ++j) m = fmaxf(m, scr[j]);
    float l = 0.f;
#pragma unroll
    for (int j = 0; j < 17; ++j) { scr[j] = __expf(scr[j] - m); l += scr[j]; }
    const float inv = 1.f / l;

    // PV: out[gr][c*16+i] = sum_j p[j] * V[s][c*16+i].
    float acc[16];
#pragma unroll
    for (int i = 0; i < 16; ++i) acc[i] = 0.f;
#pragma unroll
    for (int j = 0; j < 17; ++j) {
        float vv[16];
        load16f(&lv[(lr0 + j) * LROW + c * 16], vv);
#pragma unroll
        for (int i = 0; i < 16; ++i) acc[i] = fmaf(scr[j], vv[i], acc[i]);
    }

    // ctx store (f32, 64 B/lane contiguous).
    float* cp = &ctx[qoff];
#pragma unroll
    for (int i = 0; i < 16; i += 4) {
        float4 v = {acc[i] * inv, acc[i + 1] * inv, acc[i + 2] * inv, acc[i + 3] * inv};
        *(float4*)&cp[i] = v;
    }

    // Publish band probabilities, then stream full rows (zeros + band).
    for (int j = c; j < 17; j += 4) pband[lr0][j] = scr[j] * inv;
    __syncthreads();

    const size_t rowbase = ((size_t)bh * SEQ + t0) * SEQ;
    for (int i = tid; i < 64 * 512; i += 256) {
        const int row = i >> 9;                 // 0..63
        const int c4 = i & 511;                 // float4 index in row
        const int t = t0 + row;
        const int s_lo = (t - 16 < 0) ? 0 : t - 16;
        const int col0 = c4 * 4;
        float4 v = {0.f, 0.f, 0.f, 0.f};
        if (col0 + 3 >= s_lo && col0 <= t) {
            float vv[4];
#pragma unroll
            for (int k = 0; k < 4; ++k) {
                const int col = col0 + k;
                vv[k] = (col >= s_lo && col <= t) ? pband[row][col - (t - 16)] : 0.f;
            }
            v.x = vv[0]; v.y = vv[1]; v.z = vv[2]; v.w = vv[3];
        }
        *(float4*)&attn_out[rowbase + (size_t)row * SEQ + col0] = v;
    }
}

// ---------------------------------------------------------------------------
// ws layout: [Qp|Kp|Vp: bf16 3x8MB][WT: bf16 4x512KB][Ctx: f32 16MB] ~= 42 MB
// ---------------------------------------------------------------------------
extern "C" void kernel_launch(void* const* d_in, const int* in_sizes, int n_in,
                              void* d_out, int out_size, void* d_ws, size_t ws_size,
                              hipStream_t stream) {
    const float* queries = (const float*)d_in[0];
    const float* keys    = (const float*)d_in[1];
    const float* values  = (const float*)d_in[2];
    // d_in[3] attn_mask: fixed causal triu — folded analytically.
    const float* Wq = (const float*)d_in[4];
    const float* bq = (const float*)d_in[5];
    const float* Wk = (const float*)d_in[6];
    const float* bk = (const float*)d_in[7];
    const float* Wv = (const float*)d_in[8];
    const float* bv = (const float*)d_in[9];
    const float* Wo = (const float*)d_in[10];
    const float* bo = (const float*)d_in[11];
    const float* gamma = (const float*)d_in[12];

    char* ws = (char*)d_ws;
    unsigned short* Qp  = (unsigned short*)ws;
    unsigned short* Kp  = Qp + PROJ_ELEMS;
    unsigned short* Vp  = Kp + PROJ_ELEMS;
    unsigned short* WT  = Vp + PROJ_ELEMS;
    unsigned short* WqT = WT;
    unsigned short* WkT = WT + 262144;
    unsigned short* WvT = WT + 2 * 262144;
    unsigned short* WoT = WT + 3 * 262144;
    float* Ctx = (float*)(WT + 4 * 262144);

    float* out_p  = (float*)d_out;            // [8192,512] f32
    float* attn_p = out_p + PROJ_ELEMS;       // [65536,2048] f32

    // 1) weight transposes (f32 in, bf16 out)
    TransArgs ta;
    ta.W[0] = Wq;  ta.W[1] = Wk;  ta.W[2] = Wv;  ta.W[3] = Wo;
    ta.Wt[0] = WqT; ta.Wt[1] = WkT; ta.Wt[2] = WvT; ta.Wt[3] = WoT;
    transpose_k<<<dim3(16, 16, 4), dim3(32, 8), 0, stream>>>(ta);

    // 2) fused QKV projections (f32 A staged->bf16; bf16 out to ws)
    GemmArgs gq;
    gq.A[0] = queries; gq.A[1] = keys;  gq.A[2] = values;
    gq.Wt[0] = WqT;    gq.Wt[1] = WkT;  gq.Wt[2] = WvT;
    gq.bias[0] = bq;   gq.bias[1] = bk; gq.bias[2] = bv;
    gq.C[0] = Qp;      gq.C[1] = Kp;    gq.C[2] = Vp;
    gemm_bt<0><<<dim3(M_TOT / 128, D_MODEL / 128, 3), 256, 0, stream>>>(gq);

    // 3) tiled band attention: full f32 attn rows (band + zeros) + f32 ctx
    attn2_k<<<dim3(SEQ / 64, B_SZ * N_HEADS), 256, 0, stream>>>(
        Qp, Kp, Vp, gamma, attn_p, Ctx);

    // 4) output projection -> f32 out region of d_out
    GemmArgs go;
    go.A[0] = Ctx;   go.Wt[0] = WoT; go.bias[0] = bo; go.C[0] = out_p;
    go.A[1] = Ctx;   go.Wt[1] = WoT; go.bias[1] = bo; go.C[1] = out_p;
    go.A[2] = Ctx;   go.Wt[2] = WoT; go.bias[2] = bo; go.C[2] = out_p;
    gemm_bt<1><<<dim3(M_TOT / 128, D_MODEL / 128, 1), 256, 0, stream>>>(go);
}